// Round 1
// baseline (368.714 us; speedup 1.0000x reference)
//
#include <hip/hip_runtime.h>
#include <math.h>

// Problem constants (fixed by the reference):
//   x: [B=16, C=256, H=128, W=128] fp32
//   w: [1, 2, 7, 7] fp32
//   out: [16, 1, 128, 128] fp32 = sigmoid(conv2d(concat(mean_c(x), max_c(x)), w, pad=3))
// The fft2->ifft2 round trip is the identity on the real part -> skipped.

#define BB 16
#define CC 256
#define HH 128
#define WW 128
#define HW (HH * WW)          // 16384
#define CHW (CC * HW)         // 4194304
#define HW4 (HW / 4)          // 4096 float4 groups per plane
#define NPOS (BB * HW)        // 262144 output pixels
#define NG (BB * HW4)         // 65536 float4 groups total

// ---------------------------------------------------------------------------
// Kernel 1: per-pixel channel mean + max over C=256.
// Grid: NG/64 = 1024 blocks x 256 threads.
// Block = 64 float4-groups (lanes) x 4 channel-quarters (waves).
// Each thread: 64 strided float4 loads (stride = HW floats = 64 KB), i.e. each
// wave-load is 64 lanes x 16 B = 1 KB contiguous -> fully coalesced.
// Partials combined through LDS; wave of tid<64 writes avg/max float4s to s.
// s layout: [B][2][H][W], channel 0 = avg, channel 1 = max.
// ---------------------------------------------------------------------------
__global__ __launch_bounds__(256) void reduce_mean_max_kernel(
    const float* __restrict__ x, float* __restrict__ s) {
  const int tid  = threadIdx.x;
  const int lane = tid & 63;        // float4 group within block
  const int q    = tid >> 6;        // channel quarter 0..3 (wave id)
  const int g    = blockIdx.x * 64 + lane;  // global float4 group
  const int b    = g >> 12;         // g / 4096
  const int off  = g & 4095;        // float4 index within the HxW plane

  const float4* p = (const float4*)(x + (size_t)b * CHW) + off + (size_t)(q * 64) * HW4;

  float4 sum = make_float4(0.f, 0.f, 0.f, 0.f);
  float4 mx  = make_float4(-INFINITY, -INFINITY, -INFINITY, -INFINITY);

#pragma unroll 8
  for (int i = 0; i < 64; ++i) {
    float4 v = p[(size_t)i * HW4];
    sum.x += v.x; sum.y += v.y; sum.z += v.z; sum.w += v.w;
    mx.x = fmaxf(mx.x, v.x); mx.y = fmaxf(mx.y, v.y);
    mx.z = fmaxf(mx.z, v.z); mx.w = fmaxf(mx.w, v.w);
  }

  __shared__ float4 s_sum[4][64];
  __shared__ float4 s_max[4][64];
  s_sum[q][lane] = sum;
  s_max[q][lane] = mx;
  __syncthreads();

  if (tid < 64) {
    float4 ts = s_sum[0][tid];
    float4 tm = s_max[0][tid];
#pragma unroll
    for (int qq = 1; qq < 4; ++qq) {
      float4 a = s_sum[qq][tid];
      float4 m = s_max[qq][tid];
      ts.x += a.x; ts.y += a.y; ts.z += a.z; ts.w += a.w;
      tm.x = fmaxf(tm.x, m.x); tm.y = fmaxf(tm.y, m.y);
      tm.z = fmaxf(tm.z, m.z); tm.w = fmaxf(tm.w, m.w);
    }
    const float inv_c = 1.0f / (float)CC;
    ts.x *= inv_c; ts.y *= inv_c; ts.z *= inv_c; ts.w *= inv_c;

    float4* outa = (float4*)(s + (size_t)b * 2 * HW) + off;        // channel 0: avg
    float4* outm = (float4*)(s + (size_t)b * 2 * HW + HW) + off;   // channel 1: max
    *outa = ts;
    *outm = tm;
  }
}

// ---------------------------------------------------------------------------
// Kernel 2: 2->1 channel 7x7 'same' cross-correlation (pad 3) + sigmoid.
// One thread per output pixel; weights (98 floats) staged in LDS; input s
// (8 MB) served from L1/L2 with heavy neighborhood reuse.
// ---------------------------------------------------------------------------
__global__ __launch_bounds__(256) void conv_sigmoid_kernel(
    const float* __restrict__ s, const float* __restrict__ w,
    float* __restrict__ out) {
  __shared__ float wf[2 * 49];
  const int tid = threadIdx.x;
  if (tid < 2 * 49) wf[tid] = w[tid];
  __syncthreads();

  const int idx = blockIdx.x * 256 + tid;  // 0 .. NPOS-1
  const int b   = idx >> 14;               // / 16384
  const int hw  = idx & 16383;
  const int y   = hw >> 7;
  const int xpo = hw & 127;

  const float* sb = s + (size_t)b * 2 * HW;

  float acc = 0.0f;
#pragma unroll
  for (int ci = 0; ci < 2; ++ci) {
    const float* sc = sb + ci * HW;
    const float* wc = wf + ci * 49;
#pragma unroll
    for (int kh = 0; kh < 7; ++kh) {
      const int yy = y + kh - 3;
      if (yy < 0 || yy >= HH) continue;
      const float* row = sc + yy * WW;
#pragma unroll
      for (int kw = 0; kw < 7; ++kw) {
        const int xx = xpo + kw - 3;
        if (xx < 0 || xx >= WW) continue;
        acc = fmaf(row[xx], wc[kh * 7 + kw], acc);
      }
    }
  }

  out[idx] = 1.0f / (1.0f + expf(-acc));
}

extern "C" void kernel_launch(void* const* d_in, const int* in_sizes, int n_in,
                              void* d_out, int out_size, void* d_ws, size_t ws_size,
                              hipStream_t stream) {
  const float* x = (const float*)d_in[0];
  const float* w = (const float*)d_in[1];
  float* out = (float*)d_out;
  float* s   = (float*)d_ws;  // [16][2][128][128] fp32 = 8 MB scratch

  // Kernel 1: 65536 float4 groups / 64 per block = 1024 blocks.
  reduce_mean_max_kernel<<<NG / 64, 256, 0, stream>>>(x, s);

  // Kernel 2: 262144 pixels / 256 = 1024 blocks.
  conv_sigmoid_kernel<<<NPOS / 256, 256, 0, stream>>>(s, w, out);
}

// Round 3
// 361.600 us; speedup vs baseline: 1.0197x; 1.0197x over previous
//
#include <hip/hip_runtime.h>
#include <math.h>

// Problem constants (fixed by the reference):
//   x: [B=16, C=256, H=128, W=128] fp32
//   w: [1, 2, 7, 7] fp32
//   out: [16, 1, 128, 128] fp32 = sigmoid(conv2d(concat(mean_c(x), max_c(x)), w, pad=3))
// The fft2->ifft2 round trip is the identity on the real part -> skipped.

#define BB 16
#define CC 256
#define HH 128
#define WW 128
#define HW (HH * WW)          // 16384
#define CHW (CC * HW)         // 4194304
#define HW4 (HW / 4)          // 4096 float4 groups per plane
#define NPOS (BB * HW)        // 262144 output pixels
#define NG (BB * HW4)         // 65536 float4 groups total

// Native vector type: __builtin_nontemporal_load requires a real vector,
// not HIP_vector_type's struct wrapper.
typedef float floatx4 __attribute__((ext_vector_type(4)));

// ---------------------------------------------------------------------------
// Kernel 1: per-pixel channel mean + max over C=256.
// Grid: 1024 blocks x 512 threads (8 waves/block, 2 blocks/CU -> 32 waves/CU,
// the occupancy max). Block = 64 float4-groups (lanes) x 8 channel-eighths
// (waves). Each thread: 32 strided 16B loads (stride = 64 KB); each wave-load
// is 64 lanes x 16 B = 1 KB contiguous -> fully coalesced.
// x is streamed once -> non-temporal loads keep L2 free for the s intermediate.
// s layout: [B][2][H][W], channel 0 = avg, channel 1 = max.
// ---------------------------------------------------------------------------
__global__ __launch_bounds__(512) void reduce_mean_max_kernel(
    const float* __restrict__ x, float* __restrict__ s) {
  const int tid  = threadIdx.x;
  const int lane = tid & 63;        // float4 group within block
  const int q    = tid >> 6;        // channel eighth 0..7 (wave id)
  const int g    = blockIdx.x * 64 + lane;  // global float4 group
  const int b    = g >> 12;         // g / 4096
  const int off  = g & 4095;        // float4 index within the HxW plane

  const floatx4* p =
      (const floatx4*)(x + (size_t)b * CHW) + off + (size_t)(q * 32) * HW4;

  floatx4 sum = (floatx4)(0.f);
  floatx4 mx  = (floatx4)(-INFINITY);

#pragma unroll 8
  for (int i = 0; i < 32; ++i) {
    floatx4 v = __builtin_nontemporal_load(p + (size_t)i * HW4);
    sum += v;
    mx.x = fmaxf(mx.x, v.x); mx.y = fmaxf(mx.y, v.y);
    mx.z = fmaxf(mx.z, v.z); mx.w = fmaxf(mx.w, v.w);
  }

  __shared__ floatx4 s_sum[8][64];
  __shared__ floatx4 s_max[8][64];
  s_sum[q][lane] = sum;
  s_max[q][lane] = mx;
  __syncthreads();

  if (tid < 64) {
    floatx4 ts = s_sum[0][tid];
    floatx4 tm = s_max[0][tid];
#pragma unroll
    for (int qq = 1; qq < 8; ++qq) {
      floatx4 a = s_sum[qq][tid];
      floatx4 m = s_max[qq][tid];
      ts += a;
      tm.x = fmaxf(tm.x, m.x); tm.y = fmaxf(tm.y, m.y);
      tm.z = fmaxf(tm.z, m.z); tm.w = fmaxf(tm.w, m.w);
    }
    ts *= (1.0f / (float)CC);

    floatx4* outa = (floatx4*)(s + (size_t)b * 2 * HW) + off;        // ch 0: avg
    floatx4* outm = (floatx4*)(s + (size_t)b * 2 * HW + HW) + off;   // ch 1: max
    *outa = ts;
    *outm = tm;
  }
}

// ---------------------------------------------------------------------------
// Kernel 2: 2->1 channel 7x7 'same' cross-correlation (pad 3) + sigmoid.
// One thread per output pixel; weights (98 floats) staged in LDS; input s
// (2 MB) served from L1/L2 with heavy neighborhood reuse.
// ---------------------------------------------------------------------------
__global__ __launch_bounds__(256) void conv_sigmoid_kernel(
    const float* __restrict__ s, const float* __restrict__ w,
    float* __restrict__ out) {
  __shared__ float wf[2 * 49];
  const int tid = threadIdx.x;
  if (tid < 2 * 49) wf[tid] = w[tid];
  __syncthreads();

  const int idx = blockIdx.x * 256 + tid;  // 0 .. NPOS-1
  const int b   = idx >> 14;               // / 16384
  const int hw  = idx & 16383;
  const int y   = hw >> 7;
  const int xpo = hw & 127;

  const float* sb = s + (size_t)b * 2 * HW;

  float acc = 0.0f;
#pragma unroll
  for (int ci = 0; ci < 2; ++ci) {
    const float* sc = sb + ci * HW;
    const float* wc = wf + ci * 49;
#pragma unroll
    for (int kh = 0; kh < 7; ++kh) {
      const int yy = y + kh - 3;
      if (yy < 0 || yy >= HH) continue;
      const float* row = sc + yy * WW;
#pragma unroll
      for (int kw = 0; kw < 7; ++kw) {
        const int xx = xpo + kw - 3;
        if (xx < 0 || xx >= WW) continue;
        acc = fmaf(row[xx], wc[kh * 7 + kw], acc);
      }
    }
  }

  out[idx] = 1.0f / (1.0f + expf(-acc));
}

extern "C" void kernel_launch(void* const* d_in, const int* in_sizes, int n_in,
                              void* d_out, int out_size, void* d_ws, size_t ws_size,
                              hipStream_t stream) {
  const float* x = (const float*)d_in[0];
  const float* w = (const float*)d_in[1];
  float* out = (float*)d_out;
  float* s   = (float*)d_ws;  // [16][2][128][128] fp32 = 2 MB scratch

  // Kernel 1: 65536 float4 groups / 64 per block = 1024 blocks x 512 threads.
  reduce_mean_max_kernel<<<NG / 64, 512, 0, stream>>>(x, s);

  // Kernel 2: 262144 pixels / 256 = 1024 blocks.
  conv_sigmoid_kernel<<<NPOS / 256, 256, 0, stream>>>(s, w, out);
}